// Round 5
// baseline (277.415 us; speedup 1.0000x reference)
//
#include <hip/hip_runtime.h>
#include <hip/hip_bf16.h>
#include <stdint.h>

#define M_POS 0.5f
#define M_NEG 0.1f
#define LAM_NEG 1.0f

typedef __attribute__((ext_vector_type(4))) float floatx4;  // 16x16 MFMA accumulator
typedef __attribute__((ext_vector_type(8))) int   intx8;    // 32B fp8 operand (K=128)
typedef __attribute__((ext_vector_type(4))) int   int32x4;

union Frag8 { intx8 v; int4 q[2]; };

// ---------------- Kernel A: row sumsq, inv_norm, fp32 -> fp8(e4m3) quantize, zero accs ----
// Row-major cb_q (R20 reverts R18/R19's fragment-linear layout; keeps R19's 16B stores).
__global__ __launch_bounds__(256) void prep_kernel(
    const float* __restrict__ cb, unsigned char* __restrict__ cb_q,
    float* __restrict__ sq, float* __restrict__ inv_norm,
    unsigned* __restrict__ zero_base, int zero_len,
    int N, int d)
{
    const int gi = blockIdx.x * 256 + threadIdx.x;
    if (gi < zero_len) zero_base[gi] = 0u;

    const int t = threadIdx.x;
    const int w = t >> 6, l = t & 63;
    const int row = blockIdx.x * 4 + w;
    if (row >= N) return;
    const float* src = cb + (size_t)row * d;
    unsigned char* dst = cb_q + (size_t)row * d;

    float s = 0.f;
    for (int c = l * 16; c < d; c += 1024) {
        float4 v0 = *(const float4*)(src + c);
        float4 v1 = *(const float4*)(src + c + 4);
        float4 v2 = *(const float4*)(src + c + 8);
        float4 v3 = *(const float4*)(src + c + 12);
        s += v0.x*v0.x + v0.y*v0.y + v0.z*v0.z + v0.w*v0.w
           + v1.x*v1.x + v1.y*v1.y + v1.z*v1.z + v1.w*v1.w
           + v2.x*v2.x + v2.y*v2.y + v2.z*v2.z + v2.w*v2.w
           + v3.x*v3.x + v3.y*v3.y + v3.z*v3.z + v3.w*v3.w;
        int p0 = __builtin_amdgcn_cvt_pk_fp8_f32(v0.x, v0.y, 0, false);
        p0     = __builtin_amdgcn_cvt_pk_fp8_f32(v0.z, v0.w, p0, true);
        int p1 = __builtin_amdgcn_cvt_pk_fp8_f32(v1.x, v1.y, 0, false);
        p1     = __builtin_amdgcn_cvt_pk_fp8_f32(v1.z, v1.w, p1, true);
        int p2 = __builtin_amdgcn_cvt_pk_fp8_f32(v2.x, v2.y, 0, false);
        p2     = __builtin_amdgcn_cvt_pk_fp8_f32(v2.z, v2.w, p2, true);
        int p3 = __builtin_amdgcn_cvt_pk_fp8_f32(v3.x, v3.y, 0, false);
        p3     = __builtin_amdgcn_cvt_pk_fp8_f32(v3.z, v3.w, p3, true);
        int32x4 pk; pk.x = p0; pk.y = p1; pk.z = p2; pk.w = p3;
        *(int32x4*)(dst + c) = pk;
    }
    for (int o = 32; o > 0; o >>= 1) s += __shfl_down(s, o, 64);
    if (l == 0) { sq[row] = s; inv_norm[row] = rsqrtf(s); }
}

// ---------------- Kernel B: fused symmetric MX-fp8 Gram GEMM + loss epilogue + finalize ----
// R20: DEEP COUNTED-VMCNT RING. Aggregate evidence from R15-R19 (all ~147-160us, MfmaUtil
// 6-9%): delivered staging BW = 3.6 TB/s vs 13.4 TB/s for the m97 GEMM through the SAME
// global_load_lds path -> Little's law says we average ~1 outstanding 1KB load per CU.
// Every prior structure (barrier drain R15, dbuf drain R17, builtin prefetch R18 [sunk],
// asm prefetch R19 [VGPR=108: spilled]) degenerates to depth~1. Fix depth directly:
// 4 LDS slots x 32KB (1 kt each, 128KB total, 1 block/CU), issue ALL FOUR chunks up
// front, counted ladder vmcnt 24,24,24,24,24,16,8,0; restage slot kt&3 with chunk kt+4
// after the read-done barrier. Each wave holds ~24 loads (24KB) in flight at all times;
// 4 waves = 96KB/CU in flight (vs 3.5KB now). Staging + fragment reads are R15's
// verified code (lane-linear LDS dst, xor swizzle) -- untouched.
// Canaries: LDS=131KB, VGPR 140-190 (no spill), bank-conflict ~4.26M (R15's reads).
// DO-NOTs: per-kt vmcnt(0) drains (R15/R17); builtin reg prefetch (R18: compiler sinks);
// asm reg prefetch via union outputs (R19: regalloc spills, VGPR=108); row-major direct
// frag loads (R16: 32-line fan-out); per-thread fences (R3); 32x32x64 MX (R6);
// 1-wave blocks (R14).
__global__ __launch_bounds__(256, 1) void gram_loss_kernel(
    const unsigned char* __restrict__ A,   // N x d fp8, row-major
    const float* __restrict__ sq, const float* __restrict__ inv_norm,
    const int* __restrict__ starts, const int* __restrict__ ends,
    const int* __restrict__ max_ip,
    float* __restrict__ pos_acc, float* __restrict__ neg_acc,
    unsigned* __restrict__ counter, float* __restrict__ out,
    int N, int d)
{
    const int M = min(N, max_ip[0] + 1);

    // XCD-aware remap: contiguous tile ranges per XCD (nBlocks divisible by 8).
    int vt = blockIdx.x;
    const int nB = gridDim.x;
    if ((nB & 7) == 0) {
        const int per = nB >> 3;
        vt = (blockIdx.x & 7) * per + (blockIdx.x >> 3);
    }

    // triangular decode: vt -> (by, bx), by <= bx
    int bx = (int)((sqrtf(8.f * (float)vt + 1.f) - 1.f) * 0.5f);
    while ((bx + 1) * (bx + 2) / 2 <= vt) bx++;
    while (bx * (bx + 1) / 2 > vt) bx--;
    const int by = vt - bx * (bx + 1) / 2;

    const int rowBase = by * 128;
    const int colBase = bx * 128;
    const bool isDiag = (by == bx);

    // 4 ring slots, one 128-row x 128-byte K-tile each, per matrix: 4*16KB*2 = 128KB
    __shared__ alignas(16) unsigned char ldsA[4][128 * 128];
    __shared__ alignas(16) unsigned char ldsB[4][128 * 128];

    const int tid  = threadIdx.x;
    const int wave = tid >> 6;
    const int lane = tid & 63;
    const int wr = (wave >> 1) * 64;
    const int wc = (wave & 1) * 64;

    floatx4 acc[4][4];
#pragma unroll
    for (int a = 0; a < 4; ++a)
#pragma unroll
        for (int b = 0; b < 4; ++b) acc[a][b] = (floatx4){0.f, 0.f, 0.f, 0.f};

    // staging geometry (R15-verified): dst = slotbase + lane*16 (lane-linear),
    // src chunk xor-swizzled so the fragment read below sees the operand layout.
    const int sRow = lane >> 3;                         // 0..7
    const int sChk = lane & 7;                          // 16B chunk 0..7
    const int srcOffC = ((sChk ^ sRow) * 16);
    const int kTiles = d / 128;                         // 8

    // fragment-read constants (R15-verified)
    const int rl = lane & 15;
    const int g  = lane >> 4;       // 0..3 (k-group)
    const int rx = rl & 7;
    const int c0 = (((2 * g)     ^ rx) * 16);
    const int c1 = (((2 * g + 1) ^ rx) * 16);

#define STAGE(SLOT, KT)                                                         \
    { const int k0_ = (KT) * 128;                                               \
      _Pragma("unroll")                                                         \
      for (int h = 0; h < 4; ++h) {                                             \
        const int r_ = wave * 32 + h * 8 + sRow;                                \
        const unsigned char* ga_ = A + (size_t)(rowBase + r_) * d + k0_ + srcOffC; \
        const unsigned char* gb_ = A + (size_t)(colBase + r_) * d + k0_ + srcOffC; \
        __builtin_amdgcn_global_load_lds(                                       \
            (const __attribute__((address_space(1))) void*)ga_,                 \
            (__attribute__((address_space(3))) void*)(ldsA[SLOT] + r_ * 128 + sChk * 16), 16, 0, 0); \
        __builtin_amdgcn_global_load_lds(                                       \
            (const __attribute__((address_space(1))) void*)gb_,                 \
            (__attribute__((address_space(3))) void*)(ldsB[SLOT] + r_ * 128 + sChk * 16), 16, 0, 0); \
      } }

#define COMPUTE(SLOT)                                                           \
    { Frag8 af[4], bf[4];                                                       \
      _Pragma("unroll")                                                         \
      for (int t4 = 0; t4 < 4; ++t4) {                                          \
        const unsigned char* pa = ldsA[SLOT] + (wr + t4 * 16 + rl) * 128;       \
        af[t4].q[0] = *(const int4*)(pa + c0);                                  \
        af[t4].q[1] = *(const int4*)(pa + c1);                                  \
        const unsigned char* pb = ldsB[SLOT] + (wc + t4 * 16 + rl) * 128;       \
        bf[t4].q[0] = *(const int4*)(pb + c0);                                  \
        bf[t4].q[1] = *(const int4*)(pb + c1);                                  \
      }                                                                         \
      _Pragma("unroll")                                                         \
      for (int rt = 0; rt < 4; ++rt)                                            \
        _Pragma("unroll")                                                       \
        for (int ct = 0; ct < 4; ++ct)                                          \
          acc[rt][ct] = __builtin_amdgcn_mfma_scale_f32_16x16x128_f8f6f4(       \
              af[rt].v, bf[ct].v, acc[rt][ct], 0, 0, 0, 127, 0, 127); }

#define WAITV(NN)  asm volatile("s_waitcnt vmcnt(" #NN ")" ::: "memory")
#define WAITL0     asm volatile("s_waitcnt lgkmcnt(0)" ::: "memory")

    if (kTiles == 8) {
        // fill the ring: 4 chunks x 8 loads/thread, order pinned chunk-by-chunk
        STAGE(0, 0) __builtin_amdgcn_sched_barrier(0);
        STAGE(1, 1) __builtin_amdgcn_sched_barrier(0);
        STAGE(2, 2) __builtin_amdgcn_sched_barrier(0);
        STAGE(3, 3) __builtin_amdgcn_sched_barrier(0);
#pragma unroll
        for (int kt = 0; kt < 8; ++kt) {
            // ladder: own S(kt) retired when outstanding <= ladder[kt]
            if      (kt < 5)  WAITV(24);
            else if (kt == 5) WAITV(16);
            else if (kt == 6) WAITV(8);
            else              WAITV(0);
            __builtin_amdgcn_s_barrier();       // all waves' S(kt) visible
            COMPUTE(kt & 3)
            if (kt + 4 < 8) {
                WAITL0;                          // my ds_reads of this slot done
                __builtin_amdgcn_s_barrier();    // everyone done reading the slot
                STAGE(kt & 3, kt + 4)            // refill; stays in flight across phases
                __builtin_amdgcn_sched_barrier(0);
            }
        }
    } else {
        // generic fallback (not used at d=1024): simple drain loop on slot 0
        for (int kt = 0; kt < kTiles; ++kt) {
            STAGE(0, kt)
            WAITV(0);
            __builtin_amdgcn_s_barrier();
            COMPUTE(0)
            WAITL0;
            __builtin_amdgcn_s_barrier();
        }
    }
#undef STAGE
#undef COMPUTE
#undef WAITV
#undef WAITL0

    // ---- epilogue (16x16 C/D: col=lane&15, row=(lane>>4)*4+reg) ----
    const int q  = lane >> 4;
    const int jlo = colBase + wc;
    const int ilo = rowBase + wr;

    int   jn[4];
    float jinv[4];
    bool  jvalid[4];
#pragma unroll
    for (int ct = 0; ct < 4; ++ct) {
        const int j = jlo + ct * 16 + rl;
        jn[ct]  = j;
        jinv[ct] = inv_norm[j];
        jvalid[ct] = (j < M);
    }

    // wave-uniform positive-pair possibility check
    bool posLane = false;
    {
        const int ri = ilo + lane;
        if (ri < M) posLane |= (ends[ri] >= jlo) && (starts[ri] <= jlo + 63);
        if (!isDiag) {
            const int cj = jlo + lane;
            if (cj < M) posLane |= (ends[cj] >= ilo) && (starts[cj] <= ilo + 63);
        }
    }
    const bool fullPath = (__ballot(posLane) != 0ULL);

    float posc[4] = {0.f, 0.f, 0.f, 0.f};
    float negc[4] = {0.f, 0.f, 0.f, 0.f};

    if (fullPath) {
        int   jns[4], jne[4];
        float jsq[4];
#pragma unroll
        for (int ct = 0; ct < 4; ++ct) {
            jsq[ct] = sq[jn[ct]];
            jns[ct] = jvalid[ct] ? starts[jn[ct]] : 0;
            jne[ct] = jvalid[ct] ? ends[jn[ct]]   : -1;
        }
#pragma unroll
        for (int rt = 0; rt < 4; ++rt) {
            const int ibase = ilo + rt * 16 + q * 4;
#pragma unroll
            for (int reg = 0; reg < 4; ++reg) {
                const int i = ibase + reg;
                const bool rowValid = (i < M);
                const int ns = rowValid ? starts[i] : 0;
                const int ne = rowValid ? ends[i]   : -1;
                const float iinv = inv_norm[i];
                const float isq  = sq[i];
                float posp = 0.f, negp = 0.f;
#pragma unroll
                for (int ct = 0; ct < 4; ++ct) {
                    const float dot = acc[rt][ct][reg];
                    const int j = jn[ct];
                    float cosv = dot * iinv * jinv[ct];
                    cosv = fminf(fmaxf(cosv, -1.f), 1.f);
                    float tn = fmaxf(fabsf(cosv) - M_NEG, 0.f);
                    const float nterm = tn * tn;
                    const float d2 = fmaxf(isq + jsq[ct] - 2.f * dot, 0.f);
                    float tp = fmaxf(sqrtf(d2) - M_POS, 0.f);
                    const float pterm = tp * tp;
                    const bool dg = (j == i);
                    if (rowValid) {
                        const bool in_r = (j >= ns) && (j <= ne);
                        if (in_r && !dg) posp += pterm;
                        if (!in_r || dg) negp += nterm;
                    }
                    if (!isDiag && jvalid[ct]) {
                        const bool in_c = (i >= jns[ct]) && (i <= jne[ct]);
                        if (in_c && !dg) posc[ct] += pterm;
                        if (!in_c || dg) negc[ct] += nterm;
                    }
                }
#pragma unroll
                for (int m = 1; m < 16; m <<= 1) {
                    posp += __shfl_xor(posp, m, 64);
                    negp += __shfl_xor(negp, m, 64);
                }
                if (rowValid && rl == 0) {
                    atomicAdd(&pos_acc[i], posp);
                    atomicAdd(&neg_acc[i], negp);
                }
            }
        }
        if (!isDiag) {
#pragma unroll
            for (int ct = 0; ct < 4; ++ct) {
                posc[ct] += __shfl_xor(posc[ct], 16, 64);
                posc[ct] += __shfl_xor(posc[ct], 32, 64);
                negc[ct] += __shfl_xor(negc[ct], 16, 64);
                negc[ct] += __shfl_xor(negc[ct], 32, 64);
            }
            if (q == 0) {
#pragma unroll
                for (int ct = 0; ct < 4; ++ct) {
                    if (jvalid[ct]) {
                        atomicAdd(&pos_acc[jn[ct]], posc[ct]);
                        atomicAdd(&neg_acc[jn[ct]], negc[ct]);
                    }
                }
            }
        }
    } else {
        // fast path: every element is a negative for both its row and its column
#pragma unroll
        for (int rt = 0; rt < 4; ++rt) {
            const int ibase = ilo + rt * 16 + q * 4;
#pragma unroll
            for (int reg = 0; reg < 4; ++reg) {
                const int i = ibase + reg;
                const float iinv = inv_norm[i];
                float negp = 0.f;
#pragma unroll
                for (int ct = 0; ct < 4; ++ct) {
                    const float dot = acc[rt][ct][reg];
                    float cosv = dot * iinv * jinv[ct];
                    cosv = fminf(fmaxf(cosv, -1.f), 1.f);
                    float tn = fmaxf(fabsf(cosv) - M_NEG, 0.f);
                    const float nterm = tn * tn;
                    negp += nterm;
                    negc[ct] += nterm;
                }
#pragma unroll
                for (int m = 1; m < 16; m <<= 1)
                    negp += __shfl_xor(negp, m, 64);
                if ((i < M) && rl == 0)
                    atomicAdd(&neg_acc[i], negp);
            }
        }
        if (!isDiag) {
#pragma unroll
            for (int ct = 0; ct < 4; ++ct) {
                negc[ct] += __shfl_xor(negc[ct], 16, 64);
                negc[ct] += __shfl_xor(negc[ct], 32, 64);
            }
            if (q == 0) {
#pragma unroll
                for (int ct = 0; ct < 4; ++ct)
                    if (jvalid[ct])
                        atomicAdd(&neg_acc[jn[ct]], negc[ct]);
            }
        }
    }

    // ---- last-block finalize (fence/atomic by tid0 only — validated R7) ----
    // finalize scratch overlaid on ldsA (K-loop done; sync'd below before use)
    struct FinSm { int amLast; float ts[4]; int cs[4]; };
    FinSm* fs = (FinSm*)&ldsA[0][0];
    __syncthreads();
    if (tid == 0) {
        __threadfence();
        unsigned old = atomicAdd(counter, 1u);
        fs->amLast = (old == (unsigned)(gridDim.x - 1)) ? 1 : 0;
    }
    __syncthreads();
    if (fs->amLast) {
        __threadfence();
        float total = 0.f;
        int cnt = 0;
        for (int i = tid; i < M; i += 256) {
            const float pa = __hip_atomic_load(&pos_acc[i], __ATOMIC_RELAXED, __HIP_MEMORY_SCOPE_AGENT);
            const float na = __hip_atomic_load(&neg_acc[i], __ATOMIC_RELAXED, __HIP_MEMORY_SCOPE_AGENT);
            const int ns = starts[i], ne = ends[i];
            const int lo = max(ns, 0), hi = min(ne, N - 1);
            const int inr = max(hi - lo + 1, 0);
            const bool dg = (i >= ns) && (i <= ne);
            const int pos_cnt = inr - (dg ? 1 : 0);
            const int neg_cnt = N - inr + (dg ? 1 : 0);
            if (pos_cnt > 0 && neg_cnt > 0) {
                total += pa / (float)max(pos_cnt, 1)
                       + LAM_NEG * na / (float)max(neg_cnt, 1);
                cnt++;
            }
        }
        for (int o = 32; o > 0; o >>= 1) {
            total += __shfl_down(total, o, 64);
            cnt   += __shfl_down(cnt, o, 64);
        }
        if ((tid & 63) == 0) { fs->ts[tid >> 6] = total; fs->cs[tid >> 6] = cnt; }
        __syncthreads();
        if (tid == 0) {
            float T = fs->ts[0] + fs->ts[1] + fs->ts[2] + fs->ts[3];
            int   C = fs->cs[0] + fs->cs[1] + fs->cs[2] + fs->cs[3];
            out[0] = (C > 0) ? T / (float)C : 0.f;
        }
    }
}

extern "C" void kernel_launch(void* const* d_in, const int* in_sizes, int n_in,
                              void* d_out, int out_size, void* d_ws, size_t ws_size,
                              hipStream_t stream) {
    const float* cb     = (const float*)d_in[0];
    const int*   starts = (const int*)d_in[1];
    const int*   ends   = (const int*)d_in[2];
    const int*   max_ip = (const int*)d_in[3];
    float* out = (float*)d_out;

    const int N = in_sizes[1];
    const int d = in_sizes[0] / N;

    char* ws = (char*)d_ws;
    unsigned char* cb_q = (unsigned char*)ws;
    size_t off = ((size_t)N * d + 255) & ~(size_t)255;
    float* sq       = (float*)(ws + off); off += (size_t)N * 4;
    float* inv_norm = (float*)(ws + off); off += (size_t)N * 4;
    float* pos_acc  = (float*)(ws + off); off += (size_t)N * 4;
    float* neg_acc  = (float*)(ws + off); off += (size_t)N * 4;
    unsigned* counter = (unsigned*)(ws + off); off += 256;

    // prep zeroes pos_acc/neg_acc/counter (2N+1 u32, contiguous)
    prep_kernel<<<(N + 3) / 4, 256, 0, stream>>>(cb, cb_q, sq, inv_norm,
                                                 (unsigned*)pos_acc, 2 * N + 1, N, d);

    const int nb = N / 128;
    const int nBlocks = nb * (nb + 1) / 2;   // upper-triangular tiles
    gram_loss_kernel<<<nBlocks, 256, 0, stream>>>(cb_q, sq, inv_norm, starts, ends,
                                                  max_ip, pos_acc, neg_acc, counter,
                                                  out, N, d);
}

// Round 6
// 202.365 us; speedup vs baseline: 1.3709x; 1.3709x over previous
//
#include <hip/hip_runtime.h>
#include <hip/hip_bf16.h>
#include <stdint.h>

#define M_POS 0.5f
#define M_NEG 0.1f
#define LAM_NEG 1.0f

typedef __attribute__((ext_vector_type(4))) float floatx4;  // 16x16 MFMA accumulator
typedef __attribute__((ext_vector_type(8))) int   intx8;    // 32B fp8 operand (K=128)
typedef __attribute__((ext_vector_type(4))) int   int32x4;

union Frag8 { intx8 v; int4 q[2]; };

// ---------------- Kernel A: row sumsq, inv_norm, fp32 -> fp8(e4m3) quantize, zero accs ----
__global__ __launch_bounds__(256) void prep_kernel(
    const float* __restrict__ cb, unsigned char* __restrict__ cb_q,
    float* __restrict__ sq, float* __restrict__ inv_norm,
    unsigned* __restrict__ zero_base, int zero_len,
    int N, int d)
{
    const int gi = blockIdx.x * 256 + threadIdx.x;
    if (gi < zero_len) zero_base[gi] = 0u;

    const int t = threadIdx.x;
    const int w = t >> 6, l = t & 63;
    const int row = blockIdx.x * 4 + w;
    if (row >= N) return;
    const float* src = cb + (size_t)row * d;
    unsigned char* dst = cb_q + (size_t)row * d;

    float s = 0.f;
    for (int c = l * 16; c < d; c += 1024) {
        float4 v0 = *(const float4*)(src + c);
        float4 v1 = *(const float4*)(src + c + 4);
        float4 v2 = *(const float4*)(src + c + 8);
        float4 v3 = *(const float4*)(src + c + 12);
        s += v0.x*v0.x + v0.y*v0.y + v0.z*v0.z + v0.w*v0.w
           + v1.x*v1.x + v1.y*v1.y + v1.z*v1.z + v1.w*v1.w
           + v2.x*v2.x + v2.y*v2.y + v2.z*v2.z + v2.w*v2.w
           + v3.x*v3.x + v3.y*v3.y + v3.z*v3.z + v3.w*v3.w;
        int p0 = __builtin_amdgcn_cvt_pk_fp8_f32(v0.x, v0.y, 0, false);
        p0     = __builtin_amdgcn_cvt_pk_fp8_f32(v0.z, v0.w, p0, true);
        int p1 = __builtin_amdgcn_cvt_pk_fp8_f32(v1.x, v1.y, 0, false);
        p1     = __builtin_amdgcn_cvt_pk_fp8_f32(v1.z, v1.w, p1, true);
        int p2 = __builtin_amdgcn_cvt_pk_fp8_f32(v2.x, v2.y, 0, false);
        p2     = __builtin_amdgcn_cvt_pk_fp8_f32(v2.z, v2.w, p2, true);
        int p3 = __builtin_amdgcn_cvt_pk_fp8_f32(v3.x, v3.y, 0, false);
        p3     = __builtin_amdgcn_cvt_pk_fp8_f32(v3.z, v3.w, p3, true);
        int32x4 pk; pk.x = p0; pk.y = p1; pk.z = p2; pk.w = p3;
        *(int32x4*)(dst + c) = pk;
    }
    for (int o = 32; o > 0; o >>= 1) s += __shfl_down(s, o, 64);
    if (l == 0) { sq[row] = s; inv_norm[row] = rsqrtf(s); }
}

// ---------------- Kernel B: fused symmetric MX-fp8 Gram GEMM + loss epilogue + finalize ----
// R21: 256x256 TILE, 8 WAVES, COUNTED-VMCNT PHASE-SPLIT (m201-class port to fp8 K=128).
// Evidence: R15-R20 (five schedules at 128^2) all pin 147-218us, MfmaUtil 6-9% -- the
// 128^2 structure class is exhausted (guide regime table: 128^2 quadrants null).
// 256^2 doubles compute per staged byte: per K-step/wave, 32 MFMA (~1100cy) vs 8 loads.
// Schedule per kt: vmcnt(8) [kt's loads, issued 2 K-steps (~2200cy) earlier; kt+1's 8
// stay in flight] -> barrier -> 4 phases {ds_read 2 A-frags (+4 B-frags in ph0),
// setprio(1), 8 MFMA, setprio(0)} -> barrier -> restage freed buffer with kt+2.
// vmcnt NEVER drains uncovered mid-loop (only prologue is cold). Staging + xor-swizzle
// + fragment reads are R15's verified code (row%8 invariant holds at 256 rows).
// Canaries: LDS=131072, VGPR 200-240 (>250=spill=dead), Occupancy ~25%, conflicts ~4M.
// DO-NOTs: all 128^2 schedule variants (R15 drain / R17 dbuf-drain / R18 builtin
// prefetch [sunk] / R19 asm prefetch [spilled] / R20 deep ring [1 blk/CU too few
// waves]); row-major direct frag loads (R16); per-thread fences (R3); 32x32x64 MX (R6).
__global__ __launch_bounds__(512, 1) void gram_loss_kernel(
    const unsigned char* __restrict__ A,   // N x d fp8, row-major
    const float* __restrict__ sq, const float* __restrict__ inv_norm,
    const int* __restrict__ starts, const int* __restrict__ ends,
    const int* __restrict__ max_ip,
    float* __restrict__ pos_acc, float* __restrict__ neg_acc,
    unsigned* __restrict__ counter, float* __restrict__ out,
    int N, int d)
{
    const int M = min(N, max_ip[0] + 1);

    // XCD-aware remap: contiguous tile ranges per XCD (528 % 8 == 0).
    int vt = blockIdx.x;
    const int nB = gridDim.x;
    if ((nB & 7) == 0) {
        const int per = nB >> 3;
        vt = (blockIdx.x & 7) * per + (blockIdx.x >> 3);
    }

    // triangular decode: vt -> (by, bx), by <= bx
    int bx = (int)((sqrtf(8.f * (float)vt + 1.f) - 1.f) * 0.5f);
    while ((bx + 1) * (bx + 2) / 2 <= vt) bx++;
    while (bx * (bx + 1) / 2 > vt) bx--;
    const int by = vt - bx * (bx + 1) / 2;

    const int rowBase = by * 256;
    const int colBase = bx * 256;
    const bool isDiag = (by == bx);

    // double-buffered 256-row x 128-byte K-tiles: 2 x (32KB A + 32KB B) = 128KB
    __shared__ alignas(16) unsigned char ldsA[2][256 * 128];
    __shared__ alignas(16) unsigned char ldsB[2][256 * 128];

    const int tid  = threadIdx.x;
    const int wave = tid >> 6;
    const int lane = tid & 63;
    const int wr = (wave >> 2) * 128;   // M-half: waves 0-3 -> rows 0-127, 4-7 -> 128-255
    const int wc = (wave & 3) * 64;     // N-quarter

    floatx4 acc[8][4];
#pragma unroll
    for (int a = 0; a < 8; ++a)
#pragma unroll
        for (int b = 0; b < 4; ++b) acc[a][b] = (floatx4){0.f, 0.f, 0.f, 0.f};

    // staging geometry (R15-verified pattern, 512 threads cover 64 rows/issue):
    // sRow8 = tid>>3 in [0,64): row within h-block; sChk = tid&7: 16B chunk.
    // dst = (h*64 + tid>>3)*128 + (tid&7)*16 = waveUniformBase + lane*16  (lane-linear)
    const int sRow8 = tid >> 3;
    const int sChk  = tid & 7;
    const int srcOffC = ((sChk ^ (sRow8 & 7)) * 16);   // xor-swizzled source chunk
    const int kTiles = d / 128;                        // 8

    // fragment-read constants (R15-verified): lane holds k = (lane>>4)*32 .. +31
    const int rl = lane & 15;
    const int g  = lane >> 4;
    const int rx = rl & 7;
    const int c0 = (((2 * g)     ^ rx) * 16);
    const int c1 = (((2 * g + 1) ^ rx) * 16);

#define STAGE(SLOT, KT)                                                         \
    { const int k0_ = (KT) * 128;                                               \
      _Pragma("unroll")                                                         \
      for (int h = 0; h < 4; ++h) {                                             \
        const int r_ = h * 64 + sRow8;                                          \
        const unsigned char* ga_ = A + (size_t)(rowBase + r_) * d + k0_ + srcOffC; \
        const unsigned char* gb_ = A + (size_t)(colBase + r_) * d + k0_ + srcOffC; \
        __builtin_amdgcn_global_load_lds(                                       \
            (const __attribute__((address_space(1))) void*)ga_,                 \
            (__attribute__((address_space(3))) void*)(ldsA[SLOT] + r_ * 128 + sChk * 16), 16, 0, 0); \
        __builtin_amdgcn_global_load_lds(                                       \
            (const __attribute__((address_space(1))) void*)gb_,                 \
            (__attribute__((address_space(3))) void*)(ldsB[SLOT] + r_ * 128 + sChk * 16), 16, 0, 0); \
      } }

#define WAITV(NN)  asm volatile("s_waitcnt vmcnt(" #NN ")" ::: "memory")

    if (kTiles == 8) {
        STAGE(0, 0)
        __builtin_amdgcn_sched_barrier(0);
        STAGE(1, 1)
        __builtin_amdgcn_sched_barrier(0);
#pragma unroll
        for (int kt = 0; kt < 8; ++kt) {
            const int cur = kt & 1;
            if (kt < 7) { WAITV(8); } else { WAITV(0); }   // kt's 8 retired; kt+1's in flight
            __builtin_amdgcn_s_barrier();                  // buf[cur] complete for all waves

            // B-frags for all 4 ct, read once per kt
            Frag8 bfr[4];
#pragma unroll
            for (int ct = 0; ct < 4; ++ct) {
                const unsigned char* pb = ldsB[cur] + (wc + ct * 16 + rl) * 128;
                bfr[ct].q[0] = *(const int4*)(pb + c0);
                bfr[ct].q[1] = *(const int4*)(pb + c1);
            }
            // 4 phases: 2 A-frags + 8 MFMA each
#pragma unroll
            for (int ph = 0; ph < 4; ++ph) {
                Frag8 af0, af1;
                const unsigned char* pa0 = ldsA[cur] + (wr + (2 * ph) * 16 + rl) * 128;
                const unsigned char* pa1 = ldsA[cur] + (wr + (2 * ph + 1) * 16 + rl) * 128;
                af0.q[0] = *(const int4*)(pa0 + c0);
                af0.q[1] = *(const int4*)(pa0 + c1);
                af1.q[0] = *(const int4*)(pa1 + c0);
                af1.q[1] = *(const int4*)(pa1 + c1);
                __builtin_amdgcn_s_setprio(1);
#pragma unroll
                for (int ct = 0; ct < 4; ++ct)
                    acc[2 * ph][ct] = __builtin_amdgcn_mfma_scale_f32_16x16x128_f8f6f4(
                        af0.v, bfr[ct].v, acc[2 * ph][ct], 0, 0, 0, 127, 0, 127);
#pragma unroll
                for (int ct = 0; ct < 4; ++ct)
                    acc[2 * ph + 1][ct] = __builtin_amdgcn_mfma_scale_f32_16x16x128_f8f6f4(
                        af1.v, bfr[ct].v, acc[2 * ph + 1][ct], 0, 0, 0, 127, 0, 127);
                __builtin_amdgcn_s_setprio(0);
                __builtin_amdgcn_sched_barrier(0);
            }

            __builtin_amdgcn_s_barrier();                  // all waves done reading buf[cur]
            if (kt + 2 < 8) {
                STAGE(cur, kt + 2)                         // refill freed buffer; in flight across next kt
                __builtin_amdgcn_sched_barrier(0);
            }
        }
    } else {
        // generic fallback (unused at d=1024)
        for (int kt = 0; kt < kTiles; ++kt) {
            STAGE(0, kt)
            WAITV(0);
            __builtin_amdgcn_s_barrier();
            Frag8 bfr[4];
#pragma unroll
            for (int ct = 0; ct < 4; ++ct) {
                const unsigned char* pb = ldsB[0] + (wc + ct * 16 + rl) * 128;
                bfr[ct].q[0] = *(const int4*)(pb + c0);
                bfr[ct].q[1] = *(const int4*)(pb + c1);
            }
#pragma unroll
            for (int rt = 0; rt < 8; ++rt) {
                Frag8 af;
                const unsigned char* pa = ldsA[0] + (wr + rt * 16 + rl) * 128;
                af.q[0] = *(const int4*)(pa + c0);
                af.q[1] = *(const int4*)(pa + c1);
#pragma unroll
                for (int ct = 0; ct < 4; ++ct)
                    acc[rt][ct] = __builtin_amdgcn_mfma_scale_f32_16x16x128_f8f6f4(
                        af.v, bfr[ct].v, acc[rt][ct], 0, 0, 0, 127, 0, 127);
            }
            __syncthreads();
        }
    }
#undef STAGE
#undef WAITV

    // ---- epilogue (16x16 C/D: col=lane&15, row=(lane>>4)*4+reg) ----
    const int q  = lane >> 4;
    const int jlo = colBase + wc;
    const int ilo = rowBase + wr;

    int   jn[4];
    float jinv[4];
    bool  jvalid[4];
#pragma unroll
    for (int ct = 0; ct < 4; ++ct) {
        const int j = jlo + ct * 16 + rl;
        jn[ct]  = j;
        jinv[ct] = inv_norm[j];
        jvalid[ct] = (j < M);
    }

    // wave-uniform positive-pair possibility check over the wave's 128-row x 64-col tile
    bool posLane = false;
    {
        const int ri0 = ilo + lane;
        const int ri1 = ilo + 64 + lane;
        if (ri0 < M) posLane |= (ends[ri0] >= jlo) && (starts[ri0] <= jlo + 63);
        if (ri1 < M) posLane |= (ends[ri1] >= jlo) && (starts[ri1] <= jlo + 63);
        if (!isDiag) {
            const int cj = jlo + lane;
            if (cj < M) posLane |= (ends[cj] >= ilo) && (starts[cj] <= ilo + 127);
        }
    }
    const bool fullPath = (__ballot(posLane) != 0ULL);

    float posc[4] = {0.f, 0.f, 0.f, 0.f};
    float negc[4] = {0.f, 0.f, 0.f, 0.f};

    if (fullPath) {
        int   jns[4], jne[4];
        float jsq[4];
#pragma unroll
        for (int ct = 0; ct < 4; ++ct) {
            jsq[ct] = sq[jn[ct]];
            jns[ct] = jvalid[ct] ? starts[jn[ct]] : 0;
            jne[ct] = jvalid[ct] ? ends[jn[ct]]   : -1;
        }
#pragma unroll
        for (int rt = 0; rt < 8; ++rt) {
            const int ibase = ilo + rt * 16 + q * 4;
#pragma unroll
            for (int reg = 0; reg < 4; ++reg) {
                const int i = ibase + reg;
                const bool rowValid = (i < M);
                const int ns = rowValid ? starts[i] : 0;
                const int ne = rowValid ? ends[i]   : -1;
                const float iinv = inv_norm[i];
                const float isq  = sq[i];
                float posp = 0.f, negp = 0.f;
#pragma unroll
                for (int ct = 0; ct < 4; ++ct) {
                    const float dot = acc[rt][ct][reg];
                    const int j = jn[ct];
                    float cosv = dot * iinv * jinv[ct];
                    cosv = fminf(fmaxf(cosv, -1.f), 1.f);
                    float tn = fmaxf(fabsf(cosv) - M_NEG, 0.f);
                    const float nterm = tn * tn;
                    const float d2 = fmaxf(isq + jsq[ct] - 2.f * dot, 0.f);
                    float tp = fmaxf(sqrtf(d2) - M_POS, 0.f);
                    const float pterm = tp * tp;
                    const bool dg = (j == i);
                    if (rowValid) {
                        const bool in_r = (j >= ns) && (j <= ne);
                        if (in_r && !dg) posp += pterm;
                        if (!in_r || dg) negp += nterm;
                    }
                    if (!isDiag && jvalid[ct]) {
                        const bool in_c = (i >= jns[ct]) && (i <= jne[ct]);
                        if (in_c && !dg) posc[ct] += pterm;
                        if (!in_c || dg) negc[ct] += nterm;
                    }
                }
#pragma unroll
                for (int m = 1; m < 16; m <<= 1) {
                    posp += __shfl_xor(posp, m, 64);
                    negp += __shfl_xor(negp, m, 64);
                }
                if (rowValid && rl == 0) {
                    atomicAdd(&pos_acc[i], posp);
                    atomicAdd(&neg_acc[i], negp);
                }
            }
        }
        if (!isDiag) {
#pragma unroll
            for (int ct = 0; ct < 4; ++ct) {
                posc[ct] += __shfl_xor(posc[ct], 16, 64);
                posc[ct] += __shfl_xor(posc[ct], 32, 64);
                negc[ct] += __shfl_xor(negc[ct], 16, 64);
                negc[ct] += __shfl_xor(negc[ct], 32, 64);
            }
            if (q == 0) {
#pragma unroll
                for (int ct = 0; ct < 4; ++ct) {
                    if (jvalid[ct]) {
                        atomicAdd(&pos_acc[jn[ct]], posc[ct]);
                        atomicAdd(&neg_acc[jn[ct]], negc[ct]);
                    }
                }
            }
        }
    } else {
        // fast path: every element is a negative for both its row and its column
#pragma unroll
        for (int rt = 0; rt < 8; ++rt) {
            const int ibase = ilo + rt * 16 + q * 4;
#pragma unroll
            for (int reg = 0; reg < 4; ++reg) {
                const int i = ibase + reg;
                const float iinv = inv_norm[i];
                float negp = 0.f;
#pragma unroll
                for (int ct = 0; ct < 4; ++ct) {
                    const float dot = acc[rt][ct][reg];
                    float cosv = dot * iinv * jinv[ct];
                    cosv = fminf(fmaxf(cosv, -1.f), 1.f);
                    float tn = fmaxf(fabsf(cosv) - M_NEG, 0.f);
                    const float nterm = tn * tn;
                    negp += nterm;
                    negc[ct] += nterm;
                }
#pragma unroll
                for (int m = 1; m < 16; m <<= 1)
                    negp += __shfl_xor(negp, m, 64);
                if ((i < M) && rl == 0)
                    atomicAdd(&neg_acc[i], negp);
            }
        }
        if (!isDiag) {
#pragma unroll
            for (int ct = 0; ct < 4; ++ct) {
                negc[ct] += __shfl_xor(negc[ct], 16, 64);
                negc[ct] += __shfl_xor(negc[ct], 32, 64);
            }
            if (q == 0) {
#pragma unroll
                for (int ct = 0; ct < 4; ++ct)
                    if (jvalid[ct])
                        atomicAdd(&neg_acc[jn[ct]], negc[ct]);
            }
        }
    }

    // ---- last-block finalize (fence/atomic by tid0 only — validated R7) ----
    struct FinSm { int amLast; float ts[8]; int cs[8]; };
    FinSm* fs = (FinSm*)&ldsA[0][0];
    __syncthreads();
    if (tid == 0) {
        __threadfence();
        unsigned old = atomicAdd(counter, 1u);
        fs->amLast = (old == (unsigned)(gridDim.x - 1)) ? 1 : 0;
    }
    __syncthreads();
    if (fs->amLast) {
        __threadfence();
        float total = 0.f;
        int cnt = 0;
        for (int i = tid; i < M; i += 512) {
            const float pa = __hip_atomic_load(&pos_acc[i], __ATOMIC_RELAXED, __HIP_MEMORY_SCOPE_AGENT);
            const float na = __hip_atomic_load(&neg_acc[i], __ATOMIC_RELAXED, __HIP_MEMORY_SCOPE_AGENT);
            const int ns = starts[i], ne = ends[i];
            const int lo = max(ns, 0), hi = min(ne, N - 1);
            const int inr = max(hi - lo + 1, 0);
            const bool dg = (i >= ns) && (i <= ne);
            const int pos_cnt = inr - (dg ? 1 : 0);
            const int neg_cnt = N - inr + (dg ? 1 : 0);
            if (pos_cnt > 0 && neg_cnt > 0) {
                total += pa / (float)max(pos_cnt, 1)
                       + LAM_NEG * na / (float)max(neg_cnt, 1);
                cnt++;
            }
        }
        for (int o = 32; o > 0; o >>= 1) {
            total += __shfl_down(total, o, 64);
            cnt   += __shfl_down(cnt, o, 64);
        }
        if (lane == 0) { fs->ts[wave] = total; fs->cs[wave] = cnt; }
        __syncthreads();
        if (tid == 0) {
            float T = 0.f; int C = 0;
            for (int wv = 0; wv < 8; ++wv) { T += fs->ts[wv]; C += fs->cs[wv]; }
            out[0] = (C > 0) ? T / (float)C : 0.f;
        }
    }
}

extern "C" void kernel_launch(void* const* d_in, const int* in_sizes, int n_in,
                              void* d_out, int out_size, void* d_ws, size_t ws_size,
                              hipStream_t stream) {
    const float* cb     = (const float*)d_in[0];
    const int*   starts = (const int*)d_in[1];
    const int*   ends   = (const int*)d_in[2];
    const int*   max_ip = (const int*)d_in[3];
    float* out = (float*)d_out;

    const int N = in_sizes[1];
    const int d = in_sizes[0] / N;

    char* ws = (char*)d_ws;
    unsigned char* cb_q = (unsigned char*)ws;
    size_t off = ((size_t)N * d + 255) & ~(size_t)255;
    float* sq       = (float*)(ws + off); off += (size_t)N * 4;
    float* inv_norm = (float*)(ws + off); off += (size_t)N * 4;
    float* pos_acc  = (float*)(ws + off); off += (size_t)N * 4;
    float* neg_acc  = (float*)(ws + off); off += (size_t)N * 4;
    unsigned* counter = (unsigned*)(ws + off); off += 256;

    // prep zeroes pos_acc/neg_acc/counter (2N+1 u32, contiguous)
    prep_kernel<<<(N + 3) / 4, 256, 0, stream>>>(cb, cb_q, sq, inv_norm,
                                                 (unsigned*)pos_acc, 2 * N + 1, N, d);

    const int nb = N / 256;
    const int nBlocks = nb * (nb + 1) / 2;   // upper-triangular 256x256 tiles (528 @ N=8192)
    gram_loss_kernel<<<nBlocks, 512, 0, stream>>>(cb_q, sq, inv_norm, starts, ends,
                                                  max_ip, pos_acc, neg_acc, counter,
                                                  out, N, d);
}

// Round 7
// 199.128 us; speedup vs baseline: 1.3932x; 1.0163x over previous
//
#include <hip/hip_runtime.h>
#include <hip/hip_bf16.h>
#include <stdint.h>

#define M_POS 0.5f
#define M_NEG 0.1f
#define LAM_NEG 1.0f

typedef __attribute__((ext_vector_type(4))) float floatx4;  // 16x16 MFMA accumulator
typedef __attribute__((ext_vector_type(8))) int   intx8;    // 32B fp8 operand (K=128)
typedef __attribute__((ext_vector_type(4))) int   int32x4;

union Frag8 { intx8 v; int4 q[2]; };

// ---------------- Kernel A: row sumsq, inv_norm, fp32 -> fp8(e4m3) quantize, zero accs ----
__global__ __launch_bounds__(256) void prep_kernel(
    const float* __restrict__ cb, unsigned char* __restrict__ cb_q,
    float* __restrict__ sq, float* __restrict__ inv_norm,
    unsigned* __restrict__ zero_base, int zero_len,
    int N, int d)
{
    const int gi = blockIdx.x * 256 + threadIdx.x;
    if (gi < zero_len) zero_base[gi] = 0u;

    const int t = threadIdx.x;
    const int w = t >> 6, l = t & 63;
    const int row = blockIdx.x * 4 + w;
    if (row >= N) return;
    const float* src = cb + (size_t)row * d;
    unsigned char* dst = cb_q + (size_t)row * d;

    float s = 0.f;
    for (int c = l * 16; c < d; c += 1024) {
        float4 v0 = *(const float4*)(src + c);
        float4 v1 = *(const float4*)(src + c + 4);
        float4 v2 = *(const float4*)(src + c + 8);
        float4 v3 = *(const float4*)(src + c + 12);
        s += v0.x*v0.x + v0.y*v0.y + v0.z*v0.z + v0.w*v0.w
           + v1.x*v1.x + v1.y*v1.y + v1.z*v1.z + v1.w*v1.w
           + v2.x*v2.x + v2.y*v2.y + v2.z*v2.z + v2.w*v2.w
           + v3.x*v3.x + v3.y*v3.y + v3.z*v3.z + v3.w*v3.w;
        int p0 = __builtin_amdgcn_cvt_pk_fp8_f32(v0.x, v0.y, 0, false);
        p0     = __builtin_amdgcn_cvt_pk_fp8_f32(v0.z, v0.w, p0, true);
        int p1 = __builtin_amdgcn_cvt_pk_fp8_f32(v1.x, v1.y, 0, false);
        p1     = __builtin_amdgcn_cvt_pk_fp8_f32(v1.z, v1.w, p1, true);
        int p2 = __builtin_amdgcn_cvt_pk_fp8_f32(v2.x, v2.y, 0, false);
        p2     = __builtin_amdgcn_cvt_pk_fp8_f32(v2.z, v2.w, p2, true);
        int p3 = __builtin_amdgcn_cvt_pk_fp8_f32(v3.x, v3.y, 0, false);
        p3     = __builtin_amdgcn_cvt_pk_fp8_f32(v3.z, v3.w, p3, true);
        int32x4 pk; pk.x = p0; pk.y = p1; pk.z = p2; pk.w = p3;
        *(int32x4*)(dst + c) = pk;
    }
    for (int o = 32; o > 0; o >>= 1) s += __shfl_down(s, o, 64);
    if (l == 0) { sq[row] = s; inv_norm[row] = rsqrtf(s); }
}

// ---------------- Kernel B: fused symmetric MX-fp8 Gram GEMM + loss epilogue + finalize ----
// R22 = R21 (256^2, 8 waves, dbuf, counted vmcnt(8): 129us, 549 TF-equiv ~= guide's
// 2-phase grouped-GEMM figure) + FAITHFUL m201 PHASE STRUCTURE:
//   per kt, 4 phases {ds_read 2 A-frags (ph0:+4 B) | issue slice of kt+2 staging ->
//   s_barrier -> lgkmcnt(0) -> setprio(1) -> 8 MFMA -> setprio(0) -> s_barrier}.
// Distributed restage targets only DEAD LDS regions (derived from read schedule):
//   B[cur] fully read in ph0 -> restage at ph1 top; A h0/h2 (rows 0-63/128-191) die
//   after ph1 -> restage at ph2 top; A h1/h3 die after ph3 -> restage post-ph3.
// Per-thread issue stays 8/kt FIFO -> kt-top wait stays vmcnt(8); never 0 mid-loop.
// Mechanism (m196/m201): R21 bunched all 8 issues in the inter-kt gap -> 256 CUs slam
// L2 in lockstep 16MB bursts with no compute cover; distributing 2-4 issues per phase
// hides issue under MFMA and smooths L2 demand. Barrier pairs bound wave drift ->
// setprio has something to arbitrate (m218b).
// DO-NOTs: all 128^2 variants (R15-R20); bulk-at-kt-end restage w/o phase barriers
// (R21, superseded); builtin reg prefetch (R18); asm reg prefetch (R19); deep ring
// 1blk/CU 4-wave (R20); row-major direct frags (R16); per-thread fences (R3).
__global__ __launch_bounds__(512, 1) void gram_loss_kernel(
    const unsigned char* __restrict__ A,   // N x d fp8, row-major
    const float* __restrict__ sq, const float* __restrict__ inv_norm,
    const int* __restrict__ starts, const int* __restrict__ ends,
    const int* __restrict__ max_ip,
    float* __restrict__ pos_acc, float* __restrict__ neg_acc,
    unsigned* __restrict__ counter, float* __restrict__ out,
    int N, int d)
{
    const int M = min(N, max_ip[0] + 1);

    // XCD-aware remap: contiguous tile ranges per XCD (528 % 8 == 0).
    int vt = blockIdx.x;
    const int nB = gridDim.x;
    if ((nB & 7) == 0) {
        const int per = nB >> 3;
        vt = (blockIdx.x & 7) * per + (blockIdx.x >> 3);
    }

    // triangular decode: vt -> (by, bx), by <= bx
    int bx = (int)((sqrtf(8.f * (float)vt + 1.f) - 1.f) * 0.5f);
    while ((bx + 1) * (bx + 2) / 2 <= vt) bx++;
    while (bx * (bx + 1) / 2 > vt) bx--;
    const int by = vt - bx * (bx + 1) / 2;

    const int rowBase = by * 256;
    const int colBase = bx * 256;
    const bool isDiag = (by == bx);

    // double-buffered 256-row x 128-byte K-tiles: 2 x (32KB A + 32KB B) = 128KB
    __shared__ alignas(16) unsigned char ldsA[2][256 * 128];
    __shared__ alignas(16) unsigned char ldsB[2][256 * 128];

    const int tid  = threadIdx.x;
    const int wave = tid >> 6;
    const int lane = tid & 63;
    const int wr = (wave >> 2) * 128;   // M-half
    const int wc = (wave & 3) * 64;     // N-quarter

    floatx4 acc[8][4];
#pragma unroll
    for (int a = 0; a < 8; ++a)
#pragma unroll
        for (int b = 0; b < 4; ++b) acc[a][b] = (floatx4){0.f, 0.f, 0.f, 0.f};

    // staging geometry (R15/R21-verified): 512 threads cover 64 rows per issue;
    // dst lane-linear, src chunk xor-swizzled.
    const int sRow8 = tid >> 3;
    const int sChk  = tid & 7;
    const int srcOffC = ((sChk ^ (sRow8 & 7)) * 16);
    const int kTiles = d / 128;                        // 8

    // fragment-read constants (verified)
    const int rl = lane & 15;
    const int g  = lane >> 4;
    const int rx = rl & 7;
    const int c0 = (((2 * g)     ^ rx) * 16);
    const int c1 = (((2 * g + 1) ^ rx) * 16);

#define STAGE_A(SLOT, KT, H)                                                    \
    { const int r_ = (H) * 64 + sRow8;                                          \
      const unsigned char* ga_ = A + (size_t)(rowBase + r_) * d + (KT) * 128 + srcOffC; \
      __builtin_amdgcn_global_load_lds(                                         \
          (const __attribute__((address_space(1))) void*)ga_,                   \
          (__attribute__((address_space(3))) void*)(ldsA[SLOT] + r_ * 128 + sChk * 16), 16, 0, 0); }

#define STAGE_B(SLOT, KT, H)                                                    \
    { const int r_ = (H) * 64 + sRow8;                                          \
      const unsigned char* gb_ = A + (size_t)(colBase + r_) * d + (KT) * 128 + srcOffC; \
      __builtin_amdgcn_global_load_lds(                                         \
          (const __attribute__((address_space(1))) void*)gb_,                   \
          (__attribute__((address_space(3))) void*)(ldsB[SLOT] + r_ * 128 + sChk * 16), 16, 0, 0); }

#define WAITV(NN)   asm volatile("s_waitcnt vmcnt(" #NN ")" ::: "memory")
#define WAITLGKM0   asm volatile("s_waitcnt lgkmcnt(0)" ::: "memory")
#define SBAR        __builtin_amdgcn_s_barrier()
#define SCHED0      __builtin_amdgcn_sched_barrier(0)

#define READ_A2(AF0, AF1, CUR, ROFF)                                            \
    { const unsigned char* pa0_ = ldsA[CUR] + (wr + (ROFF)      + rl) * 128;    \
      const unsigned char* pa1_ = ldsA[CUR] + (wr + (ROFF) + 16 + rl) * 128;    \
      AF0.q[0] = *(const int4*)(pa0_ + c0);  AF0.q[1] = *(const int4*)(pa0_ + c1); \
      AF1.q[0] = *(const int4*)(pa1_ + c0);  AF1.q[1] = *(const int4*)(pa1_ + c1); }

#define MFMA8(AF0, AF1, R0)                                                     \
    { _Pragma("unroll")                                                         \
      for (int ct = 0; ct < 4; ++ct)                                            \
          acc[R0][ct] = __builtin_amdgcn_mfma_scale_f32_16x16x128_f8f6f4(       \
              AF0.v, bfr[ct].v, acc[R0][ct], 0, 0, 0, 127, 0, 127);             \
      _Pragma("unroll")                                                         \
      for (int ct = 0; ct < 4; ++ct)                                            \
          acc[(R0) + 1][ct] = __builtin_amdgcn_mfma_scale_f32_16x16x128_f8f6f4( \
              AF1.v, bfr[ct].v, acc[(R0) + 1][ct], 0, 0, 0, 127, 0, 127); }

    if (kTiles == 8) {
        // prologue: stage kt0 (8 loads) then kt1 (8 loads), FIFO order
#pragma unroll
        for (int h = 0; h < 4; ++h) { STAGE_A(0, 0, h) STAGE_B(0, 0, h) }
        SCHED0;
#pragma unroll
        for (int h = 0; h < 4; ++h) { STAGE_A(1, 1, h) STAGE_B(1, 1, h) }
        SCHED0;

#pragma unroll
        for (int kt = 0; kt < 8; ++kt) {
            const int cur = kt & 1;
            if (kt < 7) { WAITV(8); } else { WAITV(0); }   // kt's 8 retired; kt+1's in flight
            SBAR;                                          // buf[cur] complete for all waves

            Frag8 bfr[4];
            Frag8 af0, af1;

            // ---- phase 0: read 4 B-frags + A rows (wr+0, wr+16) ----
#pragma unroll
            for (int ct = 0; ct < 4; ++ct) {
                const unsigned char* pb = ldsB[cur] + (wc + ct * 16 + rl) * 128;
                bfr[ct].q[0] = *(const int4*)(pb + c0);
                bfr[ct].q[1] = *(const int4*)(pb + c1);
            }
            READ_A2(af0, af1, cur, 0)
            SBAR;
            WAITLGKM0; SCHED0;
            __builtin_amdgcn_s_setprio(1);
            MFMA8(af0, af1, 0)
            __builtin_amdgcn_s_setprio(0);
            SCHED0;
            SBAR;                                          // B[cur], A rows 0-31/128-159 dead

            // ---- phase 1: read A rows (wr+32, wr+48); restage B[cur] <- kt+2 ----
            READ_A2(af0, af1, cur, 32)
            if (kt + 2 < 8) {
#pragma unroll
                for (int h = 0; h < 4; ++h) STAGE_B(cur, kt + 2, h)
            }
            SCHED0;
            SBAR;
            WAITLGKM0; SCHED0;
            __builtin_amdgcn_s_setprio(1);
            MFMA8(af0, af1, 2)
            __builtin_amdgcn_s_setprio(0);
            SCHED0;
            SBAR;                                          // A h0 (0-63) + h2 (128-191) dead

            // ---- phase 2: read A rows (wr+64, wr+80); restage A h0,h2 <- kt+2 ----
            READ_A2(af0, af1, cur, 64)
            if (kt + 2 < 8) { STAGE_A(cur, kt + 2, 0) STAGE_A(cur, kt + 2, 2) }
            SCHED0;
            SBAR;
            WAITLGKM0; SCHED0;
            __builtin_amdgcn_s_setprio(1);
            MFMA8(af0, af1, 4)
            __builtin_amdgcn_s_setprio(0);
            SCHED0;
            SBAR;

            // ---- phase 3: read A rows (wr+96, wr+112) ----
            READ_A2(af0, af1, cur, 96)
            SBAR;
            WAITLGKM0; SCHED0;
            __builtin_amdgcn_s_setprio(1);
            MFMA8(af0, af1, 6)
            __builtin_amdgcn_s_setprio(0);
            SCHED0;
            SBAR;                                          // A h1 (64-127) + h3 (192-255) dead

            if (kt + 2 < 8) { STAGE_A(cur, kt + 2, 1) STAGE_A(cur, kt + 2, 3) SCHED0; }
        }
    } else {
        // generic fallback (unused at d=1024)
        for (int kt = 0; kt < kTiles; ++kt) {
#pragma unroll
            for (int h = 0; h < 4; ++h) { STAGE_A(0, kt, h) STAGE_B(0, kt, h) }
            WAITV(0);
            __builtin_amdgcn_s_barrier();
            Frag8 bfr[4];
#pragma unroll
            for (int ct = 0; ct < 4; ++ct) {
                const unsigned char* pb = ldsB[0] + (wc + ct * 16 + rl) * 128;
                bfr[ct].q[0] = *(const int4*)(pb + c0);
                bfr[ct].q[1] = *(const int4*)(pb + c1);
            }
#pragma unroll
            for (int rt = 0; rt < 8; rt += 2) {
                Frag8 af0, af1;
                READ_A2(af0, af1, 0, rt * 16)
                WAITLGKM0; SCHED0;
                MFMA8(af0, af1, rt)
            }
            __syncthreads();
        }
    }
#undef STAGE_A
#undef STAGE_B
#undef WAITV
#undef WAITLGKM0
#undef SBAR
#undef SCHED0
#undef READ_A2
#undef MFMA8

    // ---- epilogue (16x16 C/D: col=lane&15, row=(lane>>4)*4+reg) ----
    const int q  = lane >> 4;
    const int jlo = colBase + wc;
    const int ilo = rowBase + wr;

    int   jn[4];
    float jinv[4];
    bool  jvalid[4];
#pragma unroll
    for (int ct = 0; ct < 4; ++ct) {
        const int j = jlo + ct * 16 + rl;
        jn[ct]  = j;
        jinv[ct] = inv_norm[j];
        jvalid[ct] = (j < M);
    }

    // wave-uniform positive-pair possibility check over the wave's 128-row x 64-col tile
    bool posLane = false;
    {
        const int ri0 = ilo + lane;
        const int ri1 = ilo + 64 + lane;
        if (ri0 < M) posLane |= (ends[ri0] >= jlo) && (starts[ri0] <= jlo + 63);
        if (ri1 < M) posLane |= (ends[ri1] >= jlo) && (starts[ri1] <= jlo + 63);
        if (!isDiag) {
            const int cj = jlo + lane;
            if (cj < M) posLane |= (ends[cj] >= ilo) && (starts[cj] <= ilo + 127);
        }
    }
    const bool fullPath = (__ballot(posLane) != 0ULL);

    float posc[4] = {0.f, 0.f, 0.f, 0.f};
    float negc[4] = {0.f, 0.f, 0.f, 0.f};

    if (fullPath) {
        int   jns[4], jne[4];
        float jsq[4];
#pragma unroll
        for (int ct = 0; ct < 4; ++ct) {
            jsq[ct] = sq[jn[ct]];
            jns[ct] = jvalid[ct] ? starts[jn[ct]] : 0;
            jne[ct] = jvalid[ct] ? ends[jn[ct]]   : -1;
        }
#pragma unroll
        for (int rt = 0; rt < 8; ++rt) {
            const int ibase = ilo + rt * 16 + q * 4;
#pragma unroll
            for (int reg = 0; reg < 4; ++reg) {
                const int i = ibase + reg;
                const bool rowValid = (i < M);
                const int ns = rowValid ? starts[i] : 0;
                const int ne = rowValid ? ends[i]   : -1;
                const float iinv = inv_norm[i];
                const float isq  = sq[i];
                float posp = 0.f, negp = 0.f;
#pragma unroll
                for (int ct = 0; ct < 4; ++ct) {
                    const float dot = acc[rt][ct][reg];
                    const int j = jn[ct];
                    float cosv = dot * iinv * jinv[ct];
                    cosv = fminf(fmaxf(cosv, -1.f), 1.f);
                    float tn = fmaxf(fabsf(cosv) - M_NEG, 0.f);
                    const float nterm = tn * tn;
                    const float d2 = fmaxf(isq + jsq[ct] - 2.f * dot, 0.f);
                    float tp = fmaxf(sqrtf(d2) - M_POS, 0.f);
                    const float pterm = tp * tp;
                    const bool dg = (j == i);
                    if (rowValid) {
                        const bool in_r = (j >= ns) && (j <= ne);
                        if (in_r && !dg) posp += pterm;
                        if (!in_r || dg) negp += nterm;
                    }
                    if (!isDiag && jvalid[ct]) {
                        const bool in_c = (i >= jns[ct]) && (i <= jne[ct]);
                        if (in_c && !dg) posc[ct] += pterm;
                        if (!in_c || dg) negc[ct] += nterm;
                    }
                }
#pragma unroll
                for (int m = 1; m < 16; m <<= 1) {
                    posp += __shfl_xor(posp, m, 64);
                    negp += __shfl_xor(negp, m, 64);
                }
                if (rowValid && rl == 0) {
                    atomicAdd(&pos_acc[i], posp);
                    atomicAdd(&neg_acc[i], negp);
                }
            }
        }
        if (!isDiag) {
#pragma unroll
            for (int ct = 0; ct < 4; ++ct) {
                posc[ct] += __shfl_xor(posc[ct], 16, 64);
                posc[ct] += __shfl_xor(posc[ct], 32, 64);
                negc[ct] += __shfl_xor(negc[ct], 16, 64);
                negc[ct] += __shfl_xor(negc[ct], 32, 64);
            }
            if (q == 0) {
#pragma unroll
                for (int ct = 0; ct < 4; ++ct) {
                    if (jvalid[ct]) {
                        atomicAdd(&pos_acc[jn[ct]], posc[ct]);
                        atomicAdd(&neg_acc[jn[ct]], negc[ct]);
                    }
                }
            }
        }
    } else {
        // fast path: every element is a negative for both its row and its column
#pragma unroll
        for (int rt = 0; rt < 8; ++rt) {
            const int ibase = ilo + rt * 16 + q * 4;
#pragma unroll
            for (int reg = 0; reg < 4; ++reg) {
                const int i = ibase + reg;
                const float iinv = inv_norm[i];
                float negp = 0.f;
#pragma unroll
                for (int ct = 0; ct < 4; ++ct) {
                    const float dot = acc[rt][ct][reg];
                    float cosv = dot * iinv * jinv[ct];
                    cosv = fminf(fmaxf(cosv, -1.f), 1.f);
                    float tn = fmaxf(fabsf(cosv) - M_NEG, 0.f);
                    const float nterm = tn * tn;
                    negp += nterm;
                    negc[ct] += nterm;
                }
#pragma unroll
                for (int m = 1; m < 16; m <<= 1)
                    negp += __shfl_xor(negp, m, 64);
                if ((i < M) && rl == 0)
                    atomicAdd(&neg_acc[i], negp);
            }
        }
        if (!isDiag) {
#pragma unroll
            for (int ct = 0; ct < 4; ++ct) {
                negc[ct] += __shfl_xor(negc[ct], 16, 64);
                negc[ct] += __shfl_xor(negc[ct], 32, 64);
            }
            if (q == 0) {
#pragma unroll
                for (int ct = 0; ct < 4; ++ct)
                    if (jvalid[ct])
                        atomicAdd(&neg_acc[jn[ct]], negc[ct]);
            }
        }
    }

    // ---- last-block finalize (fence/atomic by tid0 only — validated R7) ----
    struct FinSm { int amLast; float ts[8]; int cs[8]; };
    FinSm* fs = (FinSm*)&ldsA[0][0];
    __syncthreads();
    if (tid == 0) {
        __threadfence();
        unsigned old = atomicAdd(counter, 1u);
        fs->amLast = (old == (unsigned)(gridDim.x - 1)) ? 1 : 0;
    }
    __syncthreads();
    if (fs->amLast) {
        __threadfence();
        float total = 0.f;
        int cnt = 0;
        for (int i = tid; i < M; i += 512) {
            const float pa = __hip_atomic_load(&pos_acc[i], __ATOMIC_RELAXED, __HIP_MEMORY_SCOPE_AGENT);
            const float na = __hip_atomic_load(&neg_acc[i], __ATOMIC_RELAXED, __HIP_MEMORY_SCOPE_AGENT);
            const int ns = starts[i], ne = ends[i];
            const int lo = max(ns, 0), hi = min(ne, N - 1);
            const int inr = max(hi - lo + 1, 0);
            const bool dg = (i >= ns) && (i <= ne);
            const int pos_cnt = inr - (dg ? 1 : 0);
            const int neg_cnt = N - inr + (dg ? 1 : 0);
            if (pos_cnt > 0 && neg_cnt > 0) {
                total += pa / (float)max(pos_cnt, 1)
                       + LAM_NEG * na / (float)max(neg_cnt, 1);
                cnt++;
            }
        }
        for (int o = 32; o > 0; o >>= 1) {
            total += __shfl_down(total, o, 64);
            cnt   += __shfl_down(cnt, o, 64);
        }
        if (lane == 0) { fs->ts[wave] = total; fs->cs[wave] = cnt; }
        __syncthreads();
        if (tid == 0) {
            float T = 0.f; int C = 0;
            for (int wv = 0; wv < 8; ++wv) { T += fs->ts[wv]; C += fs->cs[wv]; }
            out[0] = (C > 0) ? T / (float)C : 0.f;
        }
    }
}

extern "C" void kernel_launch(void* const* d_in, const int* in_sizes, int n_in,
                              void* d_out, int out_size, void* d_ws, size_t ws_size,
                              hipStream_t stream) {
    const float* cb     = (const float*)d_in[0];
    const int*   starts = (const int*)d_in[1];
    const int*   ends   = (const int*)d_in[2];
    const int*   max_ip = (const int*)d_in[3];
    float* out = (float*)d_out;

    const int N = in_sizes[1];
    const int d = in_sizes[0] / N;

    char* ws = (char*)d_ws;
    unsigned char* cb_q = (unsigned char*)ws;
    size_t off = ((size_t)N * d + 255) & ~(size_t)255;
    float* sq       = (float*)(ws + off); off += (size_t)N * 4;
    float* inv_norm = (float*)(ws + off); off += (size_t)N * 4;
    float* pos_acc  = (float*)(ws + off); off += (size_t)N * 4;
    float* neg_acc  = (float*)(ws + off); off += (size_t)N * 4;
    unsigned* counter = (unsigned*)(ws + off); off += 256;

    // prep zeroes pos_acc/neg_acc/counter (2N+1 u32, contiguous)
    prep_kernel<<<(N + 3) / 4, 256, 0, stream>>>(cb, cb_q, sq, inv_norm,
                                                 (unsigned*)pos_acc, 2 * N + 1, N, d);

    const int nb = N / 256;
    const int nBlocks = nb * (nb + 1) / 2;   // upper-triangular 256x256 tiles (528 @ N=8192)
    gram_loss_kernel<<<nBlocks, 512, 0, stream>>>(cb_q, sq, inv_norm, starts, ends,
                                                  max_ip, pos_acc, neg_acc, counter,
                                                  out, N, d);
}